// Round 4
// baseline (200.863 us; speedup 1.0000x reference)
//
#include <hip/hip_runtime.h>
#include <math.h>

// Masked-mean BCE-with-logits:
//   bce = max(x,0) - x*t + log1p(exp(-|x|)); out = sum(bce*m)/max(sum(m),1)
//
// R1: same-address double atomics serialize (~30cy each) -> block partials.
// R2: libm log1pf ~250 VALU inst/elem -> HW __expf/__logf softplus.
// R3: VGPR_Count=16 -> only ~3 outstanding loads/wave -> latency-bound at
//     2.75 TB/s effective. Fix: 4x unrolled batch loads (12 in flight/wave).

__global__ __launch_bounds__(256) void bce_masked_partial_kernel(
    const float4* __restrict__ logits,
    const float4* __restrict__ targets,
    const int4*   __restrict__ mask,
    float2* __restrict__ partials,   // one float2 {sum, count} per block
    int n4)
{
    const int tid = blockIdx.x * blockDim.x + threadIdx.x;
    const int S   = gridDim.x * blockDim.x;

    float sum = 0.0f;
    float cnt = 0.0f;

    int i = tid;

    // Main unrolled loop: 12 independent 16B loads issued before consumption.
    for (; i + 3 * S < n4; i += 4 * S) {
        float4 x0 = logits[i];
        float4 x1 = logits[i + S];
        float4 x2 = logits[i + 2 * S];
        float4 x3 = logits[i + 3 * S];
        float4 t0 = targets[i];
        float4 t1 = targets[i + S];
        float4 t2 = targets[i + 2 * S];
        float4 t3 = targets[i + 3 * S];
        int4   m0 = mask[i];
        int4   m1 = mask[i + S];
        int4   m2 = mask[i + 2 * S];
        int4   m3 = mask[i + 3 * S];

        float4 xs[4] = {x0, x1, x2, x3};
        float4 ts[4] = {t0, t1, t2, t3};
        int4   ms[4] = {m0, m1, m2, m3};

        #pragma unroll
        for (int j = 0; j < 4; ++j) {
            float xv[4] = {xs[j].x, xs[j].y, xs[j].z, xs[j].w};
            float tv[4] = {ts[j].x, ts[j].y, ts[j].z, ts[j].w};
            int   mv[4] = {ms[j].x, ms[j].y, ms[j].z, ms[j].w};
            #pragma unroll
            for (int k = 0; k < 4; ++k) {
                float x  = xv[k];
                float sp  = __logf(1.0f + __expf(-fabsf(x)));
                float bce = fmaxf(x, 0.0f) - x * tv[k] + sp;
                float mf  = (float)mv[k];   // mask is 0/1
                sum += bce * mf;
                cnt += mf;
            }
        }
    }

    // Remainder
    for (; i < n4; i += S) {
        float4 x = logits[i];
        float4 t = targets[i];
        int4   m = mask[i];
        float xv[4] = {x.x, x.y, x.z, x.w};
        float tv[4] = {t.x, t.y, t.z, t.w};
        int   mv[4] = {m.x, m.y, m.z, m.w};
        #pragma unroll
        for (int k = 0; k < 4; ++k) {
            float xx  = xv[k];
            float sp  = __logf(1.0f + __expf(-fabsf(xx)));
            float bce = fmaxf(xx, 0.0f) - xx * tv[k] + sp;
            float mf  = (float)mv[k];
            sum += bce * mf;
            cnt += mf;
        }
    }

    // Wave-64 shuffle reduction
    #pragma unroll
    for (int off = 32; off > 0; off >>= 1) {
        sum += __shfl_down(sum, off, 64);
        cnt += __shfl_down(cnt, off, 64);
    }

    // Cross-wave reduction via LDS (4 waves per 256-thread block)
    __shared__ float2 wsum[4];
    int lane = threadIdx.x & 63;
    int wid  = threadIdx.x >> 6;
    if (lane == 0) wsum[wid] = make_float2(sum, cnt);
    __syncthreads();
    if (threadIdx.x == 0) {
        float s = 0.0f, c = 0.0f;
        #pragma unroll
        for (int w = 0; w < 4; ++w) { s += wsum[w].x; c += wsum[w].y; }
        partials[blockIdx.x] = make_float2(s, c);
    }
}

__global__ __launch_bounds__(256) void bce_finalize_kernel(
    const float2* __restrict__ partials,
    float* __restrict__ out,
    int nblocks)
{
    float sum = 0.0f, cnt = 0.0f;
    for (int i = threadIdx.x; i < nblocks; i += 256) {
        float2 p = partials[i];
        sum += p.x;
        cnt += p.y;
    }
    #pragma unroll
    for (int off = 32; off > 0; off >>= 1) {
        sum += __shfl_down(sum, off, 64);
        cnt += __shfl_down(cnt, off, 64);
    }
    __shared__ float2 wsum[4];
    int lane = threadIdx.x & 63;
    int wid  = threadIdx.x >> 6;
    if (lane == 0) wsum[wid] = make_float2(sum, cnt);
    __syncthreads();
    if (threadIdx.x == 0) {
        float s = 0.0f, c = 0.0f;
        #pragma unroll
        for (int w = 0; w < 4; ++w) { s += wsum[w].x; c += wsum[w].y; }
        out[0] = s / fmaxf(c, 1.0f);
    }
}

extern "C" void kernel_launch(void* const* d_in, const int* in_sizes, int n_in,
                              void* d_out, int out_size, void* d_ws, size_t ws_size,
                              hipStream_t stream) {
    const float4* logits  = (const float4*)d_in[0];
    const float4* targets = (const float4*)d_in[1];
    const int4*   mask    = (const int4*)d_in[2];
    float*  out      = (float*)d_out;
    float2* partials = (float2*)d_ws;

    int n  = in_sizes[0];      // 16*1024*1024, divisible by 4
    int n4 = n / 4;

    // 2048 blocks x 256 threads = 8 blocks/CU (32 waves/CU); 8 float4/thread,
    // processed as 2 unrolled batches of 4.
    int grid = 2048;
    size_t need = (size_t)grid * sizeof(float2);
    if (ws_size < need) {
        grid = (int)(ws_size / sizeof(float2));
        if (grid < 1) grid = 1;
    }

    bce_masked_partial_kernel<<<grid, 256, 0, stream>>>(logits, targets, mask, partials, n4);
    bce_finalize_kernel<<<1, 256, 0, stream>>>(partials, out, grid);
}

// Round 5
// 199.951 us; speedup vs baseline: 1.0046x; 1.0046x over previous
//
#include <hip/hip_runtime.h>
#include <math.h>

// Masked-mean BCE-with-logits:
//   bce = max(x,0) - x*t + log1p(exp(-|x|)); out = sum(bce*m)/max(sum(m),1)
//
// R1: same-address double atomics serialize -> block partials.
// R2: libm log1pf ~250 VALU inst/elem -> HW __expf/__logf softplus.
// R3: latency-bound at 2.75 TB/s; VGPR=16 -> ~3 outstanding loads/wave.
// R4: source-level 4x unroll DEFEATED by compiler (VGPR 28, dur regressed).
//     Lesson: can't raise per-wave MLP from source.
// R5: flat kernel - ONE float4-triple per thread, 16384 blocks. No loop
//     dependency; every resident wave has all 3 loads in flight at once and
//     retires fast so the CP backfills -> max TLP instead of per-wave MLP.

__global__ __launch_bounds__(256) void bce_flat_partial_kernel(
    const float4* __restrict__ logits,
    const float4* __restrict__ targets,
    const int4*   __restrict__ mask,
    float2* __restrict__ partials,   // one float2 {sum, count} per block
    int n4)
{
    int i = blockIdx.x * 256 + threadIdx.x;

    float sum = 0.0f;
    float cnt = 0.0f;

    if (i < n4) {
        float4 x = logits[i];
        float4 t = targets[i];
        int4   m = mask[i];

        float xv[4] = {x.x, x.y, x.z, x.w};
        float tv[4] = {t.x, t.y, t.z, t.w};
        int   mv[4] = {m.x, m.y, m.z, m.w};

        #pragma unroll
        for (int k = 0; k < 4; ++k) {
            float xx  = xv[k];
            float sp  = __logf(1.0f + __expf(-fabsf(xx)));   // softplus(-|x|)
            float bce = fmaxf(xx, 0.0f) - xx * tv[k] + sp;
            float mf  = (float)mv[k];   // mask is 0/1
            sum += bce * mf;
            cnt += mf;
        }
    }

    // Wave-64 shuffle reduction
    #pragma unroll
    for (int off = 32; off > 0; off >>= 1) {
        sum += __shfl_down(sum, off, 64);
        cnt += __shfl_down(cnt, off, 64);
    }

    // Cross-wave reduction via LDS (4 waves per 256-thread block)
    __shared__ float2 wsum[4];
    int lane = threadIdx.x & 63;
    int wid  = threadIdx.x >> 6;
    if (lane == 0) wsum[wid] = make_float2(sum, cnt);
    __syncthreads();
    if (threadIdx.x == 0) {
        float s = 0.0f, c = 0.0f;
        #pragma unroll
        for (int w = 0; w < 4; ++w) { s += wsum[w].x; c += wsum[w].y; }
        partials[blockIdx.x] = make_float2(s, c);
    }
}

// Fallback (ws too small for one partial per block): grid-stride version.
__global__ __launch_bounds__(256) void bce_strided_partial_kernel(
    const float4* __restrict__ logits,
    const float4* __restrict__ targets,
    const int4*   __restrict__ mask,
    float2* __restrict__ partials,
    int n4)
{
    int tid    = blockIdx.x * blockDim.x + threadIdx.x;
    int stride = gridDim.x * blockDim.x;
    float sum = 0.0f, cnt = 0.0f;
    for (int i = tid; i < n4; i += stride) {
        float4 x = logits[i];
        float4 t = targets[i];
        int4   m = mask[i];
        float xv[4] = {x.x, x.y, x.z, x.w};
        float tv[4] = {t.x, t.y, t.z, t.w};
        int   mv[4] = {m.x, m.y, m.z, m.w};
        #pragma unroll
        for (int k = 0; k < 4; ++k) {
            float xx  = xv[k];
            float sp  = __logf(1.0f + __expf(-fabsf(xx)));
            float bce = fmaxf(xx, 0.0f) - xx * tv[k] + sp;
            float mf  = (float)mv[k];
            sum += bce * mf;
            cnt += mf;
        }
    }
    #pragma unroll
    for (int off = 32; off > 0; off >>= 1) {
        sum += __shfl_down(sum, off, 64);
        cnt += __shfl_down(cnt, off, 64);
    }
    __shared__ float2 wsum[4];
    int lane = threadIdx.x & 63;
    int wid  = threadIdx.x >> 6;
    if (lane == 0) wsum[wid] = make_float2(sum, cnt);
    __syncthreads();
    if (threadIdx.x == 0) {
        float s = 0.0f, c = 0.0f;
        #pragma unroll
        for (int w = 0; w < 4; ++w) { s += wsum[w].x; c += wsum[w].y; }
        partials[blockIdx.x] = make_float2(s, c);
    }
}

__global__ __launch_bounds__(1024) void bce_finalize_kernel(
    const float2* __restrict__ partials,
    float* __restrict__ out,
    int nblocks)
{
    float sum = 0.0f, cnt = 0.0f;
    for (int i = threadIdx.x; i < nblocks; i += 1024) {
        float2 p = partials[i];
        sum += p.x;
        cnt += p.y;
    }
    #pragma unroll
    for (int off = 32; off > 0; off >>= 1) {
        sum += __shfl_down(sum, off, 64);
        cnt += __shfl_down(cnt, off, 64);
    }
    __shared__ float2 wsum[16];
    int lane = threadIdx.x & 63;
    int wid  = threadIdx.x >> 6;
    if (lane == 0) wsum[wid] = make_float2(sum, cnt);
    __syncthreads();
    if (threadIdx.x == 0) {
        float s = 0.0f, c = 0.0f;
        #pragma unroll
        for (int w = 0; w < 16; ++w) { s += wsum[w].x; c += wsum[w].y; }
        out[0] = s / fmaxf(c, 1.0f);
    }
}

extern "C" void kernel_launch(void* const* d_in, const int* in_sizes, int n_in,
                              void* d_out, int out_size, void* d_ws, size_t ws_size,
                              hipStream_t stream) {
    const float4* logits  = (const float4*)d_in[0];
    const float4* targets = (const float4*)d_in[1];
    const int4*   mask    = (const int4*)d_in[2];
    float*  out      = (float*)d_out;
    float2* partials = (float2*)d_ws;

    int n  = in_sizes[0];      // 16*1024*1024
    int n4 = n / 4;            // 4,194,304 float4 groups

    int flat_grid = (n4 + 255) / 256;   // 16384: exactly 1 float4-triple/thread
    size_t need = (size_t)flat_grid * sizeof(float2);

    if (ws_size >= need) {
        bce_flat_partial_kernel<<<flat_grid, 256, 0, stream>>>(
            logits, targets, mask, partials, n4);
        bce_finalize_kernel<<<1, 1024, 0, stream>>>(partials, out, flat_grid);
    } else {
        int grid = (int)(ws_size / sizeof(float2));
        if (grid > 2048) grid = 2048;
        if (grid < 1) grid = 1;
        bce_strided_partial_kernel<<<grid, 256, 0, stream>>>(
            logits, targets, mask, partials, n4);
        bce_finalize_kernel<<<1, 1024, 0, stream>>>(partials, out, grid);
    }
}

// Round 6
// 177.566 us; speedup vs baseline: 1.1312x; 1.1261x over previous
//
#include <hip/hip_runtime.h>
#include <math.h>

// Masked-mean BCE-with-logits:
//   bce = max(x,0) - x*t + log1p(exp(-|x|)); out = sum(bce*m)/max(sum(m),1)
//
// R1: same-address double atomics serialize -> block partials.
// R2: libm log1pf ~250 VALU inst/elem -> HW __expf/__logf softplus.
// R3: latency theory -> 73us. R4: unroll defeated by compiler (regressed).
// R5: max-TLP flat kernel -> 70us. Three structures all converge at
//     ~2.87 TB/s delivered with VALU 20% / HBM 18% -> delivery-rate ceiling.
//     Hypothesis: chip read-path ceiling ~3.0-3.2 TB/s (copy "6.3 TB/s"
//     counts r+w). This round: nontemporal loads = the one remaining lever
//     that could move a cache-path limiter. Unchanged => roofline.

typedef float  f4_t __attribute__((ext_vector_type(4)));
typedef int    i4_t __attribute__((ext_vector_type(4)));

__global__ __launch_bounds__(256) void bce_flat_partial_kernel(
    const f4_t* __restrict__ logits,
    const f4_t* __restrict__ targets,
    const i4_t* __restrict__ mask,
    float2* __restrict__ partials,   // one float2 {sum, count} per block
    int n4)
{
    int i = blockIdx.x * 256 + threadIdx.x;

    float sum = 0.0f;
    float cnt = 0.0f;

    if (i < n4) {
        f4_t x = __builtin_nontemporal_load(&logits[i]);
        f4_t t = __builtin_nontemporal_load(&targets[i]);
        i4_t m = __builtin_nontemporal_load(&mask[i]);

        #pragma unroll
        for (int k = 0; k < 4; ++k) {
            float xx  = x[k];
            float sp  = __logf(1.0f + __expf(-fabsf(xx)));   // softplus(-|x|)
            float bce = fmaxf(xx, 0.0f) - xx * t[k] + sp;
            float mf  = (float)m[k];   // mask is 0/1
            sum += bce * mf;
            cnt += mf;
        }
    }

    // Wave-64 shuffle reduction
    #pragma unroll
    for (int off = 32; off > 0; off >>= 1) {
        sum += __shfl_down(sum, off, 64);
        cnt += __shfl_down(cnt, off, 64);
    }

    // Cross-wave reduction via LDS (4 waves per 256-thread block)
    __shared__ float2 wsum[4];
    int lane = threadIdx.x & 63;
    int wid  = threadIdx.x >> 6;
    if (lane == 0) wsum[wid] = make_float2(sum, cnt);
    __syncthreads();
    if (threadIdx.x == 0) {
        float s = 0.0f, c = 0.0f;
        #pragma unroll
        for (int w = 0; w < 4; ++w) { s += wsum[w].x; c += wsum[w].y; }
        partials[blockIdx.x] = make_float2(s, c);
    }
}

// Fallback (ws too small for one partial per block): grid-stride version.
__global__ __launch_bounds__(256) void bce_strided_partial_kernel(
    const f4_t* __restrict__ logits,
    const f4_t* __restrict__ targets,
    const i4_t* __restrict__ mask,
    float2* __restrict__ partials,
    int n4)
{
    int tid    = blockIdx.x * blockDim.x + threadIdx.x;
    int stride = gridDim.x * blockDim.x;
    float sum = 0.0f, cnt = 0.0f;
    for (int i = tid; i < n4; i += stride) {
        f4_t x = __builtin_nontemporal_load(&logits[i]);
        f4_t t = __builtin_nontemporal_load(&targets[i]);
        i4_t m = __builtin_nontemporal_load(&mask[i]);
        #pragma unroll
        for (int k = 0; k < 4; ++k) {
            float xx  = x[k];
            float sp  = __logf(1.0f + __expf(-fabsf(xx)));
            float bce = fmaxf(xx, 0.0f) - xx * t[k] + sp;
            float mf  = (float)m[k];
            sum += bce * mf;
            cnt += mf;
        }
    }
    #pragma unroll
    for (int off = 32; off > 0; off >>= 1) {
        sum += __shfl_down(sum, off, 64);
        cnt += __shfl_down(cnt, off, 64);
    }
    __shared__ float2 wsum[4];
    int lane = threadIdx.x & 63;
    int wid  = threadIdx.x >> 6;
    if (lane == 0) wsum[wid] = make_float2(sum, cnt);
    __syncthreads();
    if (threadIdx.x == 0) {
        float s = 0.0f, c = 0.0f;
        #pragma unroll
        for (int w = 0; w < 4; ++w) { s += wsum[w].x; c += wsum[w].y; }
        partials[blockIdx.x] = make_float2(s, c);
    }
}

__global__ __launch_bounds__(1024) void bce_finalize_kernel(
    const float2* __restrict__ partials,
    float* __restrict__ out,
    int nblocks)
{
    float sum = 0.0f, cnt = 0.0f;
    for (int i = threadIdx.x; i < nblocks; i += 1024) {
        float2 p = partials[i];
        sum += p.x;
        cnt += p.y;
    }
    #pragma unroll
    for (int off = 32; off > 0; off >>= 1) {
        sum += __shfl_down(sum, off, 64);
        cnt += __shfl_down(cnt, off, 64);
    }
    __shared__ float2 wsum[16];
    int lane = threadIdx.x & 63;
    int wid  = threadIdx.x >> 6;
    if (lane == 0) wsum[wid] = make_float2(sum, cnt);
    __syncthreads();
    if (threadIdx.x == 0) {
        float s = 0.0f, c = 0.0f;
        #pragma unroll
        for (int w = 0; w < 16; ++w) { s += wsum[w].x; c += wsum[w].y; }
        out[0] = s / fmaxf(c, 1.0f);
    }
}

extern "C" void kernel_launch(void* const* d_in, const int* in_sizes, int n_in,
                              void* d_out, int out_size, void* d_ws, size_t ws_size,
                              hipStream_t stream) {
    const f4_t* logits  = (const f4_t*)d_in[0];
    const f4_t* targets = (const f4_t*)d_in[1];
    const i4_t* mask    = (const i4_t*)d_in[2];
    float*  out      = (float*)d_out;
    float2* partials = (float2*)d_ws;

    int n  = in_sizes[0];      // 16*1024*1024
    int n4 = n / 4;            // 4,194,304 float4 groups

    int flat_grid = (n4 + 255) / 256;   // 16384: exactly 1 float4-triple/thread
    size_t need = (size_t)flat_grid * sizeof(float2);

    if (ws_size >= need) {
        bce_flat_partial_kernel<<<flat_grid, 256, 0, stream>>>(
            logits, targets, mask, partials, n4);
        bce_finalize_kernel<<<1, 1024, 0, stream>>>(partials, out, flat_grid);
    } else {
        int grid = (int)(ws_size / sizeof(float2));
        if (grid > 2048) grid = 2048;
        if (grid < 1) grid = 1;
        bce_strided_partial_kernel<<<grid, 256, 0, stream>>>(
            logits, targets, mask, partials, n4);
        bce_finalize_kernel<<<1, 1024, 0, stream>>>(partials, out, grid);
    }
}

// Round 7
// 176.272 us; speedup vs baseline: 1.1395x; 1.0073x over previous
//
#include <hip/hip_runtime.h>
#include <math.h>

// Masked-mean BCE-with-logits:
//   bce = max(x,0) - x*t + log1p(exp(-|x|)); out = sum(bce*m)/max(sum(m),1)
//
// R1: same-address double atomics serialize -> block partials.
// R2: libm log1pf ~250 VALU inst/elem -> HW __expf/__logf softplus.
// R3-R5: three structures converged ~2.9 TB/s -> looked like a ceiling.
// R6: NONTEMPORAL loads broke it (L2-allocation churn was the limiter):
//     kernel dropped below the harness's 40us fill dispatches (>5 TB/s).
// R7: halve dispatch+epilogue overhead: unroll-2 flat (2 triples/thread,
//     6 NT loads in flight), 8192 blocks, half the partials.

typedef float  f4_t __attribute__((ext_vector_type(4)));
typedef int    i4_t __attribute__((ext_vector_type(4)));

__global__ __launch_bounds__(256) void bce_flat2_partial_kernel(
    const f4_t* __restrict__ logits,
    const f4_t* __restrict__ targets,
    const i4_t* __restrict__ mask,
    float2* __restrict__ partials,   // one float2 {sum, count} per block
    int n4)
{
    int i0 = blockIdx.x * 512 + threadIdx.x;  // first triple
    int i1 = i0 + 256;                         // second triple (coalesced)

    float sum = 0.0f;
    float cnt = 0.0f;

    if (i1 < n4) {
        // 6 independent NT loads in flight before any consumption.
        f4_t x0 = __builtin_nontemporal_load(&logits[i0]);
        f4_t x1 = __builtin_nontemporal_load(&logits[i1]);
        f4_t t0 = __builtin_nontemporal_load(&targets[i0]);
        f4_t t1 = __builtin_nontemporal_load(&targets[i1]);
        i4_t m0 = __builtin_nontemporal_load(&mask[i0]);
        i4_t m1 = __builtin_nontemporal_load(&mask[i1]);

        #pragma unroll
        for (int k = 0; k < 4; ++k) {
            float xx  = x0[k];
            float sp  = __logf(1.0f + __expf(-fabsf(xx)));
            float bce = fmaxf(xx, 0.0f) - xx * t0[k] + sp;
            float mf  = (float)m0[k];
            sum += bce * mf;
            cnt += mf;
        }
        #pragma unroll
        for (int k = 0; k < 4; ++k) {
            float xx  = x1[k];
            float sp  = __logf(1.0f + __expf(-fabsf(xx)));
            float bce = fmaxf(xx, 0.0f) - xx * t1[k] + sp;
            float mf  = (float)m1[k];
            sum += bce * mf;
            cnt += mf;
        }
    } else if (i0 < n4) {
        f4_t x0 = __builtin_nontemporal_load(&logits[i0]);
        f4_t t0 = __builtin_nontemporal_load(&targets[i0]);
        i4_t m0 = __builtin_nontemporal_load(&mask[i0]);
        #pragma unroll
        for (int k = 0; k < 4; ++k) {
            float xx  = x0[k];
            float sp  = __logf(1.0f + __expf(-fabsf(xx)));
            float bce = fmaxf(xx, 0.0f) - xx * t0[k] + sp;
            float mf  = (float)m0[k];
            sum += bce * mf;
            cnt += mf;
        }
    }

    // Wave-64 shuffle reduction
    #pragma unroll
    for (int off = 32; off > 0; off >>= 1) {
        sum += __shfl_down(sum, off, 64);
        cnt += __shfl_down(cnt, off, 64);
    }

    // Cross-wave reduction via LDS (4 waves per 256-thread block)
    __shared__ float2 wsum[4];
    int lane = threadIdx.x & 63;
    int wid  = threadIdx.x >> 6;
    if (lane == 0) wsum[wid] = make_float2(sum, cnt);
    __syncthreads();
    if (threadIdx.x == 0) {
        float s = 0.0f, c = 0.0f;
        #pragma unroll
        for (int w = 0; w < 4; ++w) { s += wsum[w].x; c += wsum[w].y; }
        partials[blockIdx.x] = make_float2(s, c);
    }
}

// Fallback (ws too small for one partial per block): grid-stride version.
__global__ __launch_bounds__(256) void bce_strided_partial_kernel(
    const f4_t* __restrict__ logits,
    const f4_t* __restrict__ targets,
    const i4_t* __restrict__ mask,
    float2* __restrict__ partials,
    int n4)
{
    int tid    = blockIdx.x * blockDim.x + threadIdx.x;
    int stride = gridDim.x * blockDim.x;
    float sum = 0.0f, cnt = 0.0f;
    for (int i = tid; i < n4; i += stride) {
        f4_t x = __builtin_nontemporal_load(&logits[i]);
        f4_t t = __builtin_nontemporal_load(&targets[i]);
        i4_t m = __builtin_nontemporal_load(&mask[i]);
        #pragma unroll
        for (int k = 0; k < 4; ++k) {
            float xx  = x[k];
            float sp  = __logf(1.0f + __expf(-fabsf(xx)));
            float bce = fmaxf(xx, 0.0f) - xx * t[k] + sp;
            float mf  = (float)m[k];
            sum += bce * mf;
            cnt += mf;
        }
    }
    #pragma unroll
    for (int off = 32; off > 0; off >>= 1) {
        sum += __shfl_down(sum, off, 64);
        cnt += __shfl_down(cnt, off, 64);
    }
    __shared__ float2 wsum[4];
    int lane = threadIdx.x & 63;
    int wid  = threadIdx.x >> 6;
    if (lane == 0) wsum[wid] = make_float2(sum, cnt);
    __syncthreads();
    if (threadIdx.x == 0) {
        float s = 0.0f, c = 0.0f;
        #pragma unroll
        for (int w = 0; w < 4; ++w) { s += wsum[w].x; c += wsum[w].y; }
        partials[blockIdx.x] = make_float2(s, c);
    }
}

__global__ __launch_bounds__(1024) void bce_finalize_kernel(
    const float2* __restrict__ partials,
    float* __restrict__ out,
    int nblocks)
{
    float sum = 0.0f, cnt = 0.0f;
    for (int i = threadIdx.x; i < nblocks; i += 1024) {
        float2 p = partials[i];
        sum += p.x;
        cnt += p.y;
    }
    #pragma unroll
    for (int off = 32; off > 0; off >>= 1) {
        sum += __shfl_down(sum, off, 64);
        cnt += __shfl_down(cnt, off, 64);
    }
    __shared__ float2 wsum[16];
    int lane = threadIdx.x & 63;
    int wid  = threadIdx.x >> 6;
    if (lane == 0) wsum[wid] = make_float2(sum, cnt);
    __syncthreads();
    if (threadIdx.x == 0) {
        float s = 0.0f, c = 0.0f;
        #pragma unroll
        for (int w = 0; w < 16; ++w) { s += wsum[w].x; c += wsum[w].y; }
        out[0] = s / fmaxf(c, 1.0f);
    }
}

extern "C" void kernel_launch(void* const* d_in, const int* in_sizes, int n_in,
                              void* d_out, int out_size, void* d_ws, size_t ws_size,
                              hipStream_t stream) {
    const f4_t* logits  = (const f4_t*)d_in[0];
    const f4_t* targets = (const f4_t*)d_in[1];
    const i4_t* mask    = (const i4_t*)d_in[2];
    float*  out      = (float*)d_out;
    float2* partials = (float2*)d_ws;

    int n  = in_sizes[0];      // 16*1024*1024
    int n4 = n / 4;            // 4,194,304 float4 groups

    int flat_grid = (n4 + 511) / 512;   // 8192: two float4-triples per thread
    size_t need = (size_t)flat_grid * sizeof(float2);

    if (ws_size >= need) {
        bce_flat2_partial_kernel<<<flat_grid, 256, 0, stream>>>(
            logits, targets, mask, partials, n4);
        bce_finalize_kernel<<<1, 1024, 0, stream>>>(partials, out, flat_grid);
    } else {
        int grid = (int)(ws_size / sizeof(float2));
        if (grid > 2048) grid = 2048;
        if (grid < 1) grid = 1;
        bce_strided_partial_kernel<<<grid, 256, 0, stream>>>(
            logits, targets, mask, partials, n4);
        bce_finalize_kernel<<<1, 1024, 0, stream>>>(partials, out, grid);
    }
}

// Round 8
// 175.321 us; speedup vs baseline: 1.1457x; 1.0054x over previous
//
#include <hip/hip_runtime.h>
#include <math.h>

// Masked-mean BCE-with-logits:
//   bce = max(x,0) - x*t + log1p(exp(-|x|)); out = sum(bce*m)/max(sum(m),1)
//
// R1: same-address double atomics serialize -> block partials.
// R2: libm log1pf ~250 VALU inst/elem -> HW __expf/__logf softplus.
// R3-R5: three structures converged ~2.9 TB/s -> looked like a ceiling.
// R6: NONTEMPORAL loads broke it (L2-allocation churn was the limiter):
//     kernel dropped below the harness's 40us fill dispatches (>5 TB/s).
// R7: unroll-2 flat: -1.3us (noise-level). Main kernel ~38-40us vs 31us
//     floor at fill-demonstrated 6.6 TB/s.
// R8: straight-line unroll-4 (12 NT loads in flight/thread, 4096 blocks).
//     Last MLP lever; unchanged total => read-path roofline.

typedef float  f4_t __attribute__((ext_vector_type(4)));
typedef int    i4_t __attribute__((ext_vector_type(4)));

__device__ __forceinline__ void bce_accum(const f4_t& x, const f4_t& t,
                                          const i4_t& m, float& sum, float& cnt)
{
    #pragma unroll
    for (int k = 0; k < 4; ++k) {
        float xx  = x[k];
        float sp  = __logf(1.0f + __expf(-fabsf(xx)));   // softplus(-|x|)
        float bce = fmaxf(xx, 0.0f) - xx * t[k] + sp;
        float mf  = (float)m[k];   // mask is 0/1
        sum += bce * mf;
        cnt += mf;
    }
}

__global__ __launch_bounds__(256) void bce_flat4_partial_kernel(
    const f4_t* __restrict__ logits,
    const f4_t* __restrict__ targets,
    const i4_t* __restrict__ mask,
    float2* __restrict__ partials,   // one float2 {sum, count} per block
    int n4)
{
    int i0 = blockIdx.x * 1024 + threadIdx.x;  // 4 coalesced triples/thread
    int i1 = i0 + 256;
    int i2 = i0 + 512;
    int i3 = i0 + 768;

    float sum = 0.0f;
    float cnt = 0.0f;

    if (i3 < n4) {
        // 12 independent NT loads issued before any consumption.
        f4_t x0 = __builtin_nontemporal_load(&logits[i0]);
        f4_t x1 = __builtin_nontemporal_load(&logits[i1]);
        f4_t x2 = __builtin_nontemporal_load(&logits[i2]);
        f4_t x3 = __builtin_nontemporal_load(&logits[i3]);
        f4_t t0 = __builtin_nontemporal_load(&targets[i0]);
        f4_t t1 = __builtin_nontemporal_load(&targets[i1]);
        f4_t t2 = __builtin_nontemporal_load(&targets[i2]);
        f4_t t3 = __builtin_nontemporal_load(&targets[i3]);
        i4_t m0 = __builtin_nontemporal_load(&mask[i0]);
        i4_t m1 = __builtin_nontemporal_load(&mask[i1]);
        i4_t m2 = __builtin_nontemporal_load(&mask[i2]);
        i4_t m3 = __builtin_nontemporal_load(&mask[i3]);

        bce_accum(x0, t0, m0, sum, cnt);
        bce_accum(x1, t1, m1, sum, cnt);
        bce_accum(x2, t2, m2, sum, cnt);
        bce_accum(x3, t3, m3, sum, cnt);
    } else {
        // Tail (not taken for n4 = 4096*1024, kept for generality).
        for (int i = i0; i < n4; i += 256) {
            f4_t x = __builtin_nontemporal_load(&logits[i]);
            f4_t t = __builtin_nontemporal_load(&targets[i]);
            i4_t m = __builtin_nontemporal_load(&mask[i]);
            bce_accum(x, t, m, sum, cnt);
        }
    }

    // Wave-64 shuffle reduction
    #pragma unroll
    for (int off = 32; off > 0; off >>= 1) {
        sum += __shfl_down(sum, off, 64);
        cnt += __shfl_down(cnt, off, 64);
    }

    // Cross-wave reduction via LDS (4 waves per 256-thread block)
    __shared__ float2 wsum[4];
    int lane = threadIdx.x & 63;
    int wid  = threadIdx.x >> 6;
    if (lane == 0) wsum[wid] = make_float2(sum, cnt);
    __syncthreads();
    if (threadIdx.x == 0) {
        float s = 0.0f, c = 0.0f;
        #pragma unroll
        for (int w = 0; w < 4; ++w) { s += wsum[w].x; c += wsum[w].y; }
        partials[blockIdx.x] = make_float2(s, c);
    }
}

// Fallback (ws too small for one partial per block): grid-stride version.
__global__ __launch_bounds__(256) void bce_strided_partial_kernel(
    const f4_t* __restrict__ logits,
    const f4_t* __restrict__ targets,
    const i4_t* __restrict__ mask,
    float2* __restrict__ partials,
    int n4)
{
    int tid    = blockIdx.x * blockDim.x + threadIdx.x;
    int stride = gridDim.x * blockDim.x;
    float sum = 0.0f, cnt = 0.0f;
    for (int i = tid; i < n4; i += stride) {
        f4_t x = __builtin_nontemporal_load(&logits[i]);
        f4_t t = __builtin_nontemporal_load(&targets[i]);
        i4_t m = __builtin_nontemporal_load(&mask[i]);
        bce_accum(x, t, m, sum, cnt);
    }
    #pragma unroll
    for (int off = 32; off > 0; off >>= 1) {
        sum += __shfl_down(sum, off, 64);
        cnt += __shfl_down(cnt, off, 64);
    }
    __shared__ float2 wsum[4];
    int lane = threadIdx.x & 63;
    int wid  = threadIdx.x >> 6;
    if (lane == 0) wsum[wid] = make_float2(sum, cnt);
    __syncthreads();
    if (threadIdx.x == 0) {
        float s = 0.0f, c = 0.0f;
        #pragma unroll
        for (int w = 0; w < 4; ++w) { s += wsum[w].x; c += wsum[w].y; }
        partials[blockIdx.x] = make_float2(s, c);
    }
}

__global__ __launch_bounds__(1024) void bce_finalize_kernel(
    const float2* __restrict__ partials,
    float* __restrict__ out,
    int nblocks)
{
    float sum = 0.0f, cnt = 0.0f;
    for (int i = threadIdx.x; i < nblocks; i += 1024) {
        float2 p = partials[i];
        sum += p.x;
        cnt += p.y;
    }
    #pragma unroll
    for (int off = 32; off > 0; off >>= 1) {
        sum += __shfl_down(sum, off, 64);
        cnt += __shfl_down(cnt, off, 64);
    }
    __shared__ float2 wsum[16];
    int lane = threadIdx.x & 63;
    int wid  = threadIdx.x >> 6;
    if (lane == 0) wsum[wid] = make_float2(sum, cnt);
    __syncthreads();
    if (threadIdx.x == 0) {
        float s = 0.0f, c = 0.0f;
        #pragma unroll
        for (int w = 0; w < 16; ++w) { s += wsum[w].x; c += wsum[w].y; }
        out[0] = s / fmaxf(c, 1.0f);
    }
}

extern "C" void kernel_launch(void* const* d_in, const int* in_sizes, int n_in,
                              void* d_out, int out_size, void* d_ws, size_t ws_size,
                              hipStream_t stream) {
    const f4_t* logits  = (const f4_t*)d_in[0];
    const f4_t* targets = (const f4_t*)d_in[1];
    const i4_t* mask    = (const i4_t*)d_in[2];
    float*  out      = (float*)d_out;
    float2* partials = (float2*)d_ws;

    int n  = in_sizes[0];      // 16*1024*1024
    int n4 = n / 4;            // 4,194,304 float4 groups

    int flat_grid = (n4 + 1023) / 1024;   // 4096: four float4-triples/thread
    size_t need = (size_t)flat_grid * sizeof(float2);

    if (ws_size >= need) {
        bce_flat4_partial_kernel<<<flat_grid, 256, 0, stream>>>(
            logits, targets, mask, partials, n4);
        bce_finalize_kernel<<<1, 1024, 0, stream>>>(partials, out, flat_grid);
    } else {
        int grid = (int)(ws_size / sizeof(float2));
        if (grid > 2048) grid = 2048;
        if (grid < 1) grid = 1;
        bce_strided_partial_kernel<<<grid, 256, 0, stream>>>(
            logits, targets, mask, partials, n4);
        bce_finalize_kernel<<<1, 1024, 0, stream>>>(partials, out, grid);
    }
}